// Round 13
// baseline (71.830 us; speedup 1.0000x reference)
//
#include <hip/hip_runtime.h>

// 5-level wavedec (filter len 8, pywt 'symmetric'), 4096 rows of 8192 f32.
// Lengths: 8192 -> 4099 -> 2053 -> 1030 -> 518 -> 262
// Out: approx(262) @0, d5(262), d4(518), d3(1030), d2(2053), d1(4099).
//
// R13: TWO ROWS PER THREAD. Each block owns rows {2b, 2b+1}; every thread
// processes group j for both rows in one straight-line body under ONE
// predicate (interior test is row-independent): 16 independent loads ->
// 128 FMA -> 16 stores. R12's two-groups-one-row failed because the two
// chains sat under different predicates (basic-block split let the
// scheduler sink chain 2); identical-j rows share the predicate, so the
// load batch cannot be split. Also halves per-row barrier/index overhead.

static constexpr int ROWS = 4096;
static constexpr int N0 = 8192;
static constexpr int L1n = 4099, L2n = 2053, L3n = 1030, L4n = 518, L5n = 262;
static constexpr size_t OFF_D5 = 1073152u;
static constexpr size_t OFF_D4 = 2146304u;
static constexpr size_t OFF_D3 = 4268032u;
static constexpr size_t OFF_D2 = 8486912u;
static constexpr size_t OFF_D1 = 16896000u;

__device__ __forceinline__ float refl_load(const float* __restrict__ s, int idx, int n) {
    int i = (idx < 0) ? (-1 - idx) : ((idx >= n) ? (2 * n - 1 - idx) : idx);
    return s[i];
}

// w[0..15] = src[8j-6 .. 8j+9] (interior groups only)
__device__ __forceinline__ void load_win(const float* __restrict__ src, int j,
                                         float* __restrict__ w) {
    const float2* __restrict__ s2 = reinterpret_cast<const float2*>(src) + (4 * j - 3);
#pragma unroll
    for (int t = 0; t < 8; ++t) {
        const float2 v = s2[t];
        w[2 * t] = v.x; w[2 * t + 1] = v.y;
    }
}

__device__ __forceinline__ void edge_group(
    const float* __restrict__ src, int n, int m,
    const float* __restrict__ h, const float* __restrict__ g,
    float* __restrict__ adst, float* __restrict__ ddst, int j)
{
#pragma unroll 4
    for (int r = 0; r < 4; ++r) {
        const int pos = 4 * j + r;
        if (pos >= m) break;
        const int s0 = 2 * pos + 1;
        float a = 0.f, d = 0.f;
#pragma unroll
        for (int q = 0; q < 8; ++q) {
            const float v = refl_load(src, s0 - q, n);
            a = fmaf(h[q], v, a);
            d = fmaf(g[q], v, d);
        }
        ddst[pos] = d;
        adst[pos] = a;
    }
}

// One DWT level for TWO rows: one predicate, two independent chains.
__device__ __forceinline__ void dwt_level2(
    const float* __restrict__ s0, const float* __restrict__ s1, int n, int m,
    const float* __restrict__ h, const float* __restrict__ g,
    float* __restrict__ a0, float* __restrict__ a1,
    float* __restrict__ d0, float* __restrict__ d1, int tid)
{
    const int G = (m + 3) >> 2;
    const int jmax = (n - 10) >> 3;   // interior iff 1 <= j <= jmax

    for (int j = tid; j < G; j += 256) {
        const int p0 = 4 * j;
        if (j >= 1 && j <= jmax && p0 + 3 < m) {
            float w0[16], w1[16];
            load_win(s0, j, w0);          // 16 independent loads,
            load_win(s1, j, w1);          // same basic block, no predicate split
            float aa0[4], dd0[4], aa1[4], dd1[4];
#pragma unroll
            for (int r = 0; r < 4; ++r) {
                float x0 = 0.f, y0 = 0.f, x1 = 0.f, y1 = 0.f;
#pragma unroll
                for (int q = 0; q < 8; ++q) {
                    const float u0 = w0[2 * r + 7 - q];   // src[2(p0+r)+1-q]
                    const float u1 = w1[2 * r + 7 - q];
                    x0 = fmaf(h[q], u0, x0);
                    y0 = fmaf(g[q], u0, y0);
                    x1 = fmaf(h[q], u1, x1);
                    y1 = fmaf(g[q], u1, y1);
                }
                aa0[r] = x0; dd0[r] = y0;
                aa1[r] = x1; dd1[r] = y1;
            }
#pragma unroll
            for (int r = 0; r < 4; ++r) d0[p0 + r] = dd0[r];
#pragma unroll
            for (int r = 0; r < 4; ++r) d1[p0 + r] = dd1[r];
#pragma unroll
            for (int r = 0; r < 4; ++r) a0[p0 + r] = aa0[r];
#pragma unroll
            for (int r = 0; r < 4; ++r) a1[p0 + r] = aa1[r];
        } else {
            edge_group(s0, n, m, h, g, a0, d0, j);
            edge_group(s1, n, m, h, g, a1, d1, j);
        }
    }
}

__global__ __launch_bounds__(256, 3)
void wavedec5_kernel(const float* __restrict__ x,
                     const float* __restrict__ dlo,
                     const float* __restrict__ dhi,
                     float* __restrict__ out)
{
    __shared__ __align__(16) float bufA[2][4100];  // a1 / a3 per row
    __shared__ __align__(16) float bufB[2][2056];  // a2 / a4 per row

    const int tid  = threadIdx.x;
    const int row0 = blockIdx.x << 1;
    const int row1 = row0 + 1;

    float h[8], g[8];
#pragma unroll
    for (int i = 0; i < 8; ++i) { h[i] = dlo[i]; g[i] = dhi[i]; }

    const float* __restrict__ xr0 = x + (size_t)row0 * N0;
    const float* __restrict__ xr1 = x + (size_t)row1 * N0;

    // L1: global -> bufA, d1 -> global
    dwt_level2(xr0, xr1, N0, L1n, h, g, bufA[0], bufA[1],
               out + OFF_D1 + (size_t)row0 * L1n,
               out + OFF_D1 + (size_t)row1 * L1n, tid);
    __syncthreads();
    // L2: bufA -> bufB, d2 -> global
    dwt_level2(bufA[0], bufA[1], L1n, L2n, h, g, bufB[0], bufB[1],
               out + OFF_D2 + (size_t)row0 * L2n,
               out + OFF_D2 + (size_t)row1 * L2n, tid);
    __syncthreads();
    // L3: bufB -> bufA, d3 -> global
    dwt_level2(bufB[0], bufB[1], L2n, L3n, h, g, bufA[0], bufA[1],
               out + OFF_D3 + (size_t)row0 * L3n,
               out + OFF_D3 + (size_t)row1 * L3n, tid);
    __syncthreads();
    // L4: bufA -> bufB, d4 -> global
    dwt_level2(bufA[0], bufA[1], L3n, L4n, h, g, bufB[0], bufB[1],
               out + OFF_D4 + (size_t)row0 * L4n,
               out + OFF_D4 + (size_t)row1 * L4n, tid);
    __syncthreads();
    // L5: bufB -> approx & d5 straight to global
    dwt_level2(bufB[0], bufB[1], L4n, L5n, h, g,
               out + (size_t)row0 * L5n, out + (size_t)row1 * L5n,
               out + OFF_D5 + (size_t)row0 * L5n,
               out + OFF_D5 + (size_t)row1 * L5n, tid);
}

extern "C" void kernel_launch(void* const* d_in, const int* in_sizes, int n_in,
                              void* d_out, int out_size, void* d_ws, size_t ws_size,
                              hipStream_t stream) {
    const float* x   = (const float*)d_in[0];
    const float* dlo = (const float*)d_in[1];
    const float* dhi = (const float*)d_in[2];
    float* out = (float*)d_out;
    wavedec5_kernel<<<ROWS / 2, 256, 0, stream>>>(x, dlo, dhi, out);
}

// Round 14
// 58.677 us; speedup vs baseline: 1.2242x; 1.2242x over previous
//
#include <hip/hip_runtime.h>

// 5-level wavedec (filter len 8, pywt 'symmetric'), 4096 rows of 8192 f32.
// Lengths: 8192 -> 4099 -> 2053 -> 1030 -> 518 -> 262
// Out: approx(262) @0, d5(262), d4(518), d3(1030), d2(2053), d1(4099).
//
// R14 = R10 (best, 58.4us) with ONE change: inter-level barriers are
// hand-rolled "s_waitcnt lgkmcnt(0); s_barrier" instead of __syncthreads().
// __syncthreads forces a vmcnt(0) drain, so every level-ending barrier
// waited on the global d-store acks (~500-900cy, x5 levels, x16 row-tasks
// per CU, all waves blocked together). Only LDS (a-buffer) needs ordering
// across levels; d-stores are never re-read by the block. This is AITER's
// "never drain vmcnt in the loop" applied to the barrier itself.

static constexpr int ROWS = 4096;
static constexpr int N0 = 8192;
static constexpr int L1n = 4099, L2n = 2053, L3n = 1030, L4n = 518, L5n = 262;
static constexpr size_t OFF_D5 = 1073152u;
static constexpr size_t OFF_D4 = 2146304u;
static constexpr size_t OFF_D3 = 4268032u;
static constexpr size_t OFF_D2 = 8486912u;
static constexpr size_t OFF_D1 = 16896000u;

// Barrier that orders LDS only: no vmcnt(0) drain of global stores.
__device__ __forceinline__ void barrier_lds() {
    asm volatile("s_waitcnt lgkmcnt(0)\n\ts_barrier" ::: "memory");
}

__device__ __forceinline__ float refl_load(const float* __restrict__ s, int idx, int n) {
    int i = (idx < 0) ? (-1 - idx) : ((idx >= n) ? (2 * n - 1 - idx) : idx);
    return s[i];
}

// Clamped 16-float window load for group j: w[t] = src[8j-6+t]
template <int N>
__device__ __forceinline__ void load_window(const float* __restrict__ src,
                                            int j, float* __restrict__ w) {
    constexpr int jmax = (N - 10) >> 3;
    const int jb = j < 1 ? 1 : (j > jmax ? jmax : j);
    const float2* __restrict__ s2 = reinterpret_cast<const float2*>(src) + (4 * jb - 3);
#pragma unroll
    for (int t = 0; t < 8; ++t) {
        const float2 v = s2[t];
        w[2 * t] = v.x; w[2 * t + 1] = v.y;
    }
}

// Branchy symmetric-reflect path for edge / partial groups.
template <int N, int M>
__device__ __forceinline__ void edge_group(
    const float* __restrict__ src,
    const float* __restrict__ h, const float* __restrict__ g,
    float* __restrict__ adst, float* __restrict__ ddst, int j)
{
#pragma unroll 4
    for (int r = 0; r < 4; ++r) {
        const int pos = 4 * j + r;
        if (pos >= M) break;
        const int s0 = 2 * pos + 1;
        float a = 0.f, d = 0.f;
#pragma unroll
        for (int q = 0; q < 8; ++q) {
            const float v = refl_load(src, s0 - q, N);
            a = fmaf(h[q], v, a);
            d = fmaf(g[q], v, d);
        }
        ddst[pos] = d;
        adst[pos] = a;
    }
}

// One DWT level, NITER windows loaded upfront.
template <int N, int M, int NITER>
__device__ __forceinline__ void dwt_level(
    const float* __restrict__ src,
    const float* __restrict__ h, const float* __restrict__ g,
    float* __restrict__ adst, float* __restrict__ ddst, int tid)
{
    constexpr int ngroups = (M + 3) >> 2;
    constexpr int jmax = (N - 10) >> 3;
    constexpr int rem = ngroups - NITER * 256;       // leftover (edge) groups
    constexpr bool full = (NITER * 256 <= ngroups);  // all t-slots valid

    float w[NITER][16];
#pragma unroll
    for (int t = 0; t < NITER; ++t) {
        const int j = tid + t * 256;
        if (full || j < ngroups)
            load_window<N>(src, j, &w[t][0]);
    }
    __builtin_amdgcn_sched_barrier(0);   // pin: loads issued before compute

#pragma unroll
    for (int t = 0; t < NITER; ++t) {
        const int j = tid + t * 256;
        if (!full && j >= ngroups) break;
        const int p0 = 4 * j;
        if (j >= 1 && j <= jmax && p0 + 3 < M) {
            float aa[4], dd[4];
#pragma unroll
            for (int r = 0; r < 4; ++r) {
                float a = 0.f, d = 0.f;
#pragma unroll
                for (int q = 0; q < 8; ++q) {
                    const float v = w[t][2 * r + 7 - q];   // src[2(p0+r)+1-q]
                    a = fmaf(h[q], v, a);
                    d = fmaf(g[q], v, d);
                }
                aa[r] = a; dd[r] = d;
            }
#pragma unroll
            for (int r = 0; r < 4; ++r) ddst[p0 + r] = dd[r];
#pragma unroll
            for (int r = 0; r < 4; ++r) adst[p0 + r] = aa[r];
        } else {
            edge_group<N, M>(src, h, g, adst, ddst, j);
        }
    }
    if constexpr (rem > 0) {
        if (tid < rem)
            edge_group<N, M>(src, h, g, adst, ddst, NITER * 256 + tid);
    }
}

__global__ __launch_bounds__(256, 4)
void wavedec5_kernel(const float* __restrict__ x,
                     const float* __restrict__ dlo,
                     const float* __restrict__ dhi,
                     float* __restrict__ out)
{
    __shared__ __align__(16) float bufA[4100];  // a1 / a3
    __shared__ __align__(16) float bufB[2056];  // a2 / a4

    const int row = blockIdx.x;
    const int tid = threadIdx.x;

    float h[8], g[8];
#pragma unroll
    for (int i = 0; i < 8; ++i) { h[i] = dlo[i]; g[i] = dhi[i]; }

    const float* __restrict__ xr = x + (size_t)row * N0;

    // L1: global -> bufA, d1 -> global
    dwt_level<N0, L1n, 4>(xr, h, g, bufA,
                          out + OFF_D1 + (size_t)row * L1n, tid);
    barrier_lds();
    // L2: bufA -> bufB, d2 -> global
    dwt_level<L1n, L2n, 2>(bufA, h, g, bufB,
                           out + OFF_D2 + (size_t)row * L2n, tid);
    barrier_lds();
    // L3: bufB -> bufA, d3 -> global
    dwt_level<L2n, L3n, 1>(bufB, h, g, bufA,
                           out + OFF_D3 + (size_t)row * L3n, tid);
    barrier_lds();
    // L4: bufA -> bufB, d4 -> global
    dwt_level<L3n, L4n, 1>(bufA, h, g, bufB,
                           out + OFF_D4 + (size_t)row * L4n, tid);
    barrier_lds();
    // L5: bufB -> approx & d5 straight to global
    dwt_level<L4n, L5n, 1>(bufB, h, g,
                           out + (size_t)row * L5n,
                           out + OFF_D5 + (size_t)row * L5n, tid);
}

extern "C" void kernel_launch(void* const* d_in, const int* in_sizes, int n_in,
                              void* d_out, int out_size, void* d_ws, size_t ws_size,
                              hipStream_t stream) {
    const float* x   = (const float*)d_in[0];
    const float* dlo = (const float*)d_in[1];
    const float* dhi = (const float*)d_in[2];
    float* out = (float*)d_out;
    wavedec5_kernel<<<ROWS, 256, 0, stream>>>(x, dlo, dhi, out);
}